// Round 23
// baseline (142.540 us; speedup 1.0000x reference)
//
#include <hip/hip_runtime.h>
#include <hip/hip_fp16.h>

#define BATCH 4096
#define IN_DIM 256
#define GRID_N 64
#define HID 128
constexpr float BN_EPS = 1e-5f;

typedef _Float16 h2 __attribute__((ext_vector_type(2)));
__device__ __forceinline__ h2 as_h2(unsigned u){ union {unsigned x; h2 h;} c; c.x = u; return c.h; }

// ---------------- workspace layout (bytes) ----------------
static const size_t O_MMP  = 0;                      // 16 partials * 512 f = 32768
static const size_t O_P1   = 32768;                  // L1 stats partials: 1024*512 f = 2 MB
static const size_t O_P2   = O_P1 + 2097152;         // 256*256 f = 256 KB
static const size_t O_P3   = O_P2 + 262144;          // 256*128 f = 128 KB
static const size_t O_SS1  = O_P3 + 131072;          // 512 f
static const size_t O_SS2  = O_SS1 + 2048;           // 256 f
static const size_t O_STB  = O_SS2 + 1024;           // packed fp16 table: 256*65*128 u32
static const size_t O_A1   = O_STB + (size_t)256*65*128*4;
static const size_t O_A2   = O_A1 + (size_t)4096*256*4;
static const size_t O_A3   = O_A2 + (size_t)4096*128*4;

// blocks 0..15: minmax partials (256 rows each).
// blocks 16..143: packed prefix tables, 2 i-columns per block
//   STb[i][K][h] = pack(fp16(S1), fp16(-S2)), i = (bid-16)*2 + (tid>>7), h = tid&127
__global__ __launch_bounds__(256) void k_prep(const float* __restrict__ x, const float* __restrict__ fs,
                                              const float* __restrict__ grids,
                                              float* __restrict__ mmp, unsigned* __restrict__ STb){
    const int tid = threadIdx.x;
    const int bid = blockIdx.x;
    if (bid < 16){
        const float* xp = x + (size_t)bid*256*IN_DIM + tid;
        float mn = 1e30f, mx = -1e30f;
        #pragma unroll 8
        for (int r = 0; r < 256; ++r){
            float v = xp[(size_t)r*IN_DIM];
            mn = fminf(mn, v); mx = fmaxf(mx, v);
        }
        mmp[(size_t)bid*512 + tid]       = mn;
        mmp[(size_t)bid*512 + 256 + tid] = mx;
        return;
    }
    const int i = (bid - 16)*2 + (tid >> 7);  // 0..255
    const int h = tid & 127;                  // 0..127
    const float* f0 = fs + ((size_t)(0*IN_DIM + i)*GRID_N)*HID + h;
    const float* f1 = fs + ((size_t)(1*IN_DIM + i)*GRID_N)*HID + h;
    const float* f2 = fs + ((size_t)(2*IN_DIM + i)*GRID_N)*HID + h;
    unsigned* st = STb + (size_t)i*65*HID + h;
    float acc1 = 0.f, acc2 = 0.f;
    st[0] = 0u;
    #pragma unroll 4
    for (int k = 0; k < 64; ++k){
        float fv = f0[(size_t)k*HID] + f1[(size_t)k*HID] + f2[(size_t)k*HID];
        float g  = grids[k];            // row 0 (identical across depth)
        acc1 += fv;
        acc2  = fmaf(g, fv, acc2);
        __half2 hh = __halves2half2(__float2half_rn(acc1), __float2half_rn(-acc2));
        st[(size_t)(k+1)*HID] = *reinterpret_cast<unsigned*>(&hh);
    }
}

// FUSED gather + layer-1 GEMM.
// 1024 blocks x 256 thr (4 waves). Each block: 4 batch rows.
// Phase A: each wave computes h[row][0..127] via dual-half-wave fdot2 -> h_lds.
// Phase B: thread t = output column t (N=256): 4 rows x K=128 from LDS (broadcast),
//          w1 coalesced; writes relu(h@w1+b1) tile + per-block column stats (no tree).
__global__ __launch_bounds__(256) void k_gather_g1(const float* __restrict__ x, const float* __restrict__ mmp,
                                                   const unsigned* __restrict__ STb,
                                                   const float* __restrict__ w1, const float* __restrict__ b1,
                                                   float* __restrict__ A1, float* __restrict__ p1){
    __shared__ float s_zmin[256], s_inv[256];
    __shared__ uint2 pre[4][256];       // (half2(z,1) bits, byte-offset) per (row_local, i)
    __shared__ float h_lds[4][128];
    const int tid = threadIdx.x;
    const int b0  = blockIdx.x * 4;

    {   // reduce 16 min/max partials (L2-hot); one feature per thread
        int f = tid;
        float mn = 1e30f, mx = -1e30f;
        #pragma unroll
        for (int p = 0; p < 16; ++p){
            mn = fminf(mn, mmp[(size_t)p*512 + f]);
            mx = fmaxf(mx, mmp[(size_t)p*512 + 256 + f]);
        }
        s_zmin[f] = mn;
        s_inv[f]  = 1.0f / (mx - mn + 1e-6f);
    }
    __syncthreads();

    for (int idx = tid; idx < 4*256; idx += 256){
        int bl = idx >> 8, i = idx & 255;
        float z = (x[(size_t)(b0 + bl)*IN_DIM + i] - s_zmin[i]) * s_inv[i];
        int K0 = (int)(z * 63.0f) + 1;
        K0 = max(1, min(63, K0));
        unsigned off = ((unsigned)(i*65 + K0)) << 9;    // row stride = 128 u32 = 512 B
        __half2 zh = __halves2half2(__float2half_rn(z), __float2half_rn(1.0f));
        pre[bl][i] = make_uint2(*reinterpret_cast<unsigned*>(&zh), off);
    }
    __syncthreads();

    {   // Phase A: wave w -> row w
        const int w  = tid >> 6;
        const int l  = tid & 63;
        const int hl = l & 31;          // h = 4*hl .. 4*hl+3
        const int hi = l >> 5;          // 0: i in [0,128), 1: [128,256)
        const char* base = (const char*)STb + (size_t)hl * 16;
        const uint2* pp = &pre[w][hi * 128];
        float acc0 = 0.f, acc1 = 0.f, acc2 = 0.f, acc3 = 0.f;
        #pragma unroll 8
        for (int ii = 0; ii < 128; ++ii){
            uint2 p = pp[ii];           // uniform per half-wave -> broadcast
            uint4 u = *reinterpret_cast<const uint4*>(base + p.y);
            h2 zz = as_h2(p.x);
            acc0 = __builtin_amdgcn_fdot2(zz, as_h2(u.x), acc0, false);
            acc1 = __builtin_amdgcn_fdot2(zz, as_h2(u.y), acc1, false);
            acc2 = __builtin_amdgcn_fdot2(zz, as_h2(u.z), acc2, false);
            acc3 = __builtin_amdgcn_fdot2(zz, as_h2(u.w), acc3, false);
        }
        acc0 += __shfl(acc0, hl + 32);
        acc1 += __shfl(acc1, hl + 32);
        acc2 += __shfl(acc2, hl + 32);
        acc3 += __shfl(acc3, hl + 32);
        if (hi == 0){
            *reinterpret_cast<float4*>(&h_lds[w][4*hl]) = make_float4(acc0, acc1, acc2, acc3);
        }
    }
    __syncthreads();

    {   // Phase B: layer-1 tile. thread t = column t.
        float a0 = 0.f, a1 = 0.f, a2 = 0.f, a3 = 0.f;
        #pragma unroll 8
        for (int k = 0; k < 128; ++k){
            float wv = w1[(size_t)k*256 + tid];     // coalesced, L2-hot
            float h0 = h_lds[0][k], h1 = h_lds[1][k], h2v = h_lds[2][k], h3 = h_lds[3][k];
            a0 = fmaf(h0, wv, a0); a1 = fmaf(h1, wv, a1);
            a2 = fmaf(h2v, wv, a2); a3 = fmaf(h3, wv, a3);
        }
        float bb = b1[tid];
        float v0 = fmaxf(a0 + bb, 0.f), v1 = fmaxf(a1 + bb, 0.f);
        float v2 = fmaxf(a2 + bb, 0.f), v3 = fmaxf(a3 + bb, 0.f);
        A1[(size_t)(b0 + 0)*256 + tid] = v0;
        A1[(size_t)(b0 + 1)*256 + tid] = v1;
        A1[(size_t)(b0 + 2)*256 + tid] = v2;
        A1[(size_t)(b0 + 3)*256 + tid] = v3;
        p1[(size_t)blockIdx.x*512 + tid]       = v0 + v1 + v2 + v3;
        p1[(size_t)blockIdx.x*512 + 256 + tid] = v0*v0 + v1*v1 + v2*v2 + v3*v3;
    }
}

// reduce per-block stats partials ONCE: stats[j] = sum_p part[p][j]
__global__ __launch_bounds__(256) void k_stats(const float* __restrict__ part, float* __restrict__ stats,
                                               int twoN, int nparts){
    int j = blockIdx.x*256 + threadIdx.x;
    if (j >= twoN) return;
    float s = 0.f;
    #pragma unroll 8
    for (int p = 0; p < nparts; ++p) s += part[(size_t)p*twoN + j];
    stats[j] = s;
}

// fp32 GEMM: C = relu(bn(A) @ W + bias); per-column stats -> per-block partials.
// tile 16x64, KC=64, 256 threads, micro-tile 1x4; grid (N/64, 256)
template<int BN_IN>
__global__ __launch_bounds__(256) void k_gemm(const float* __restrict__ A, const float* __restrict__ W,
                                              const float* __restrict__ bias,
                                              const float* __restrict__ instats,
                                              const float* __restrict__ gam, const float* __restrict__ bet,
                                              float* __restrict__ C, float* __restrict__ outpart,
                                              int K, int N){
    __shared__ float As[16][64];
    __shared__ float Ws[64][64];
    __shared__ float bnsc[256], bnsh[256];
    __shared__ float red[16][16][8];

    const int tid = threadIdx.x;
    const int n0  = blockIdx.x * 64;
    const int b0  = blockIdx.y * 16;

    if (BN_IN){
        for (int k = tid; k < K; k += 256){
            float m  = instats[k]     * (1.0f/BATCH);
            float v  = instats[K + k] * (1.0f/BATCH) - m*m;
            float rs = rsqrtf(v + BN_EPS);
            float sc = gam[k]*rs;
            bnsc[k] = sc;
            bnsh[k] = fmaf(-m, sc, bet[k]);
        }
        __syncthreads();
    }

    const int nt = tid & 15;
    const int bt = tid >> 4;
    float acc[4] = {0.f, 0.f, 0.f, 0.f};

    for (int kc = 0; kc < K; kc += 64){
        #pragma unroll
        for (int idx = tid; idx < 16*64; idx += 256){
            int r = idx >> 6, k = idx & 63;
            float a = A[(size_t)(b0 + r)*K + kc + k];
            if (BN_IN) a = fmaf(a, bnsc[kc + k], bnsh[kc + k]);
            As[r][k] = a;
        }
        #pragma unroll
        for (int idx = tid; idx < 64*64; idx += 256){
            int k = idx >> 6, n = idx & 63;
            Ws[k][n] = W[(size_t)(kc + k)*N + n0 + n];
        }
        __syncthreads();
        #pragma unroll
        for (int k = 0; k < 64; ++k){
            float4 w = *reinterpret_cast<const float4*>(&Ws[k][nt*4]);
            float a0 = As[bt][k];
            acc[0] = fmaf(a0, w.x, acc[0]); acc[1] = fmaf(a0, w.y, acc[1]);
            acc[2] = fmaf(a0, w.z, acc[2]); acc[3] = fmaf(a0, w.w, acc[3]);
        }
        __syncthreads();
    }

    float vv[4];
    #pragma unroll
    for (int j = 0; j < 4; ++j){
        float v1 = acc[j] + bias[n0 + nt*4 + j];
        vv[j] = fmaxf(v1, 0.f);
    }
    *reinterpret_cast<float4*>(&C[(size_t)(b0 + bt)*N + n0 + nt*4]) =
        make_float4(vv[0], vv[1], vv[2], vv[3]);
    #pragma unroll
    for (int j = 0; j < 4; ++j){
        red[bt][nt][j]   = vv[j];
        red[bt][nt][4+j] = vv[j]*vv[j];
    }
    __syncthreads();
    for (int s = 8; s > 0; s >>= 1){
        if (bt < s){
            #pragma unroll
            for (int f = 0; f < 8; ++f) red[bt][nt][f] += red[bt+s][nt][f];
        }
        __syncthreads();
    }
    if (bt == 0){
        float* op = outpart + (size_t)blockIdx.y*(2*N);
        #pragma unroll
        for (int j = 0; j < 4; ++j){
            op[n0 + nt*4 + j]     = red[0][nt][j];
            op[N + n0 + nt*4 + j] = red[0][nt][4+j];
        }
    }
}

// out = BN(A3) @ w4 + b4   (reduces p3[256][128] in preamble — tiny, 16 blocks)
__global__ __launch_bounds__(256) void k_final(const float* __restrict__ A3, const float* __restrict__ p3,
                                               const float* __restrict__ g3, const float* __restrict__ be3,
                                               const float* __restrict__ w4, const float* __restrict__ b4,
                                               float* __restrict__ out){
    __shared__ float psum[2][128];
    __shared__ float sc[64], sh[64];
    const int t = threadIdx.x;
    {
        int j = t & 127, half = t >> 7;
        float s = 0.f;
        #pragma unroll 8
        for (int p = half*128; p < half*128 + 128; ++p) s += p3[(size_t)p*128 + j];
        psum[half][j] = s;
    }
    __syncthreads();
    if (t < 64){
        float s  = psum[0][t]      + psum[1][t];
        float ss = psum[0][64 + t] + psum[1][64 + t];
        float m  = s  * (1.0f/BATCH);
        float v  = ss * (1.0f/BATCH) - m*m;
        float rs = rsqrtf(v + BN_EPS);
        float g  = g3[t]*rs;
        sc[t] = g * w4[t];
        sh[t] = fmaf(-m, g, be3[t]) * w4[t];
    }
    __syncthreads();
    int row = blockIdx.x*256 + t;
    const float* a = A3 + (size_t)row*64;
    float acc = b4[0];
    #pragma unroll
    for (int k = 0; k < 64; ++k){
        acc = fmaf(a[k], sc[k], acc);
        acc += sh[k];
    }
    out[row] = acc;
}

extern "C" void kernel_launch(void* const* d_in, const int* in_sizes, int n_in,
                              void* d_out, int out_size, void* d_ws, size_t ws_size,
                              hipStream_t stream){
    const float* x     = (const float*)d_in[0];
    const float* fs    = (const float*)d_in[1];
    const float* grids = (const float*)d_in[2];
    const float* w1 = (const float*)d_in[3];  const float* b1 = (const float*)d_in[4];
    const float* g1 = (const float*)d_in[5];  const float* be1= (const float*)d_in[6];
    const float* w2 = (const float*)d_in[7];  const float* b2 = (const float*)d_in[8];
    const float* g2 = (const float*)d_in[9];  const float* be2= (const float*)d_in[10];
    const float* w3 = (const float*)d_in[11]; const float* b3 = (const float*)d_in[12];
    const float* g3 = (const float*)d_in[13]; const float* be3= (const float*)d_in[14];
    const float* w4 = (const float*)d_in[15]; const float* b4 = (const float*)d_in[16];
    float* out = (float*)d_out;

    char* ws = (char*)d_ws;
    float* mmp    = (float*)(ws + O_MMP);
    float* p1     = (float*)(ws + O_P1);
    float* p2     = (float*)(ws + O_P2);
    float* p3     = (float*)(ws + O_P3);
    float* ss1    = (float*)(ws + O_SS1);
    float* ss2    = (float*)(ws + O_SS2);
    unsigned* STb = (unsigned*)(ws + O_STB);
    float* A1     = (float*)(ws + O_A1);
    float* A2     = (float*)(ws + O_A2);
    float* A3     = (float*)(ws + O_A3);

    k_prep<<<144, 256, 0, stream>>>(x, fs, grids, mmp, STb);
    k_gather_g1<<<1024, 256, 0, stream>>>(x, mmp, STb, w1, b1, A1, p1);
    k_stats<<<2, 256, 0, stream>>>(p1, ss1, 512, 1024);
    k_gemm<1><<<dim3(2, 256), 256, 0, stream>>>(A1, w2, b2, ss1, g1, be1, A2, p2, 256, 128);
    k_stats<<<1, 256, 0, stream>>>(p2, ss2, 256, 256);
    k_gemm<1><<<dim3(1, 256), 256, 0, stream>>>(A2, w3, b3, ss2, g2, be2, A3, p3, 128, 64);
    k_final<<<16, 256, 0, stream>>>(A3, p3, g3, be3, w4, b4, out);
}

// Round 24
// 100.666 us; speedup vs baseline: 1.4160x; 1.4160x over previous
//
#include <hip/hip_runtime.h>
#include <hip/hip_fp16.h>

#define BATCH 4096
#define IN_DIM 256
#define GRID_N 64
#define HID 128
#define GEMM_GB 256            // b-blocks per layer (BATCH/16)
#define PCHUNKS 16             // p-chunks in k_stats (GEMM_GB/16 rows each)
constexpr float BN_EPS = 1e-5f;

typedef _Float16 h2 __attribute__((ext_vector_type(2)));
__device__ __forceinline__ h2 as_h2(unsigned u){ union {unsigned x; h2 h;} c; c.x = u; return c.h; }

// ---------------- workspace layout (bytes) ----------------
static const size_t O_MMP  = 0;                      // 16 partials * 512 f = 32768
static const size_t O_P1   = 32768;                  // L1 stats partials: 256*512 f = 512 KB
static const size_t O_P2   = O_P1 + 524288;          // 256*256 f = 256 KB
static const size_t O_P3   = O_P2 + 262144;          // 256*128 f = 128 KB
static const size_t O_PI1  = O_P3 + 131072;          // pint1: 16*512 f = 32 KB
static const size_t O_PI2  = O_PI1 + 32768;          // pint2: 16*256 f = 16 KB
static const size_t O_STB  = O_PI2 + 16384;          // packed fp16 table: 256*65*128 u32
static const size_t O_A1   = O_STB + (size_t)256*65*128*4;
static const size_t O_A2   = O_A1 + (size_t)4096*256*4;
static const size_t O_A3   = O_A2 + (size_t)4096*128*4;

// blocks 0..15: minmax partials (256 rows each).
// blocks 16..143: packed prefix tables, 2 i-columns per block
//   STb[i][K][h] = pack(fp16(S1), fp16(-S2)), i = (bid-16)*2 + (tid>>7), h = tid&127
__global__ __launch_bounds__(256) void k_prep(const float* __restrict__ x, const float* __restrict__ fs,
                                              const float* __restrict__ grids,
                                              float* __restrict__ mmp, unsigned* __restrict__ STb){
    const int tid = threadIdx.x;
    const int bid = blockIdx.x;
    if (bid < 16){
        const float* xp = x + (size_t)bid*256*IN_DIM + tid;
        float mn = 1e30f, mx = -1e30f;
        #pragma unroll 8
        for (int r = 0; r < 256; ++r){
            float v = xp[(size_t)r*IN_DIM];
            mn = fminf(mn, v); mx = fmaxf(mx, v);
        }
        mmp[(size_t)bid*512 + tid]       = mn;
        mmp[(size_t)bid*512 + 256 + tid] = mx;
        return;
    }
    const int i = (bid - 16)*2 + (tid >> 7);  // 0..255
    const int h = tid & 127;                  // 0..127
    const float* f0 = fs + ((size_t)(0*IN_DIM + i)*GRID_N)*HID + h;
    const float* f1 = fs + ((size_t)(1*IN_DIM + i)*GRID_N)*HID + h;
    const float* f2 = fs + ((size_t)(2*IN_DIM + i)*GRID_N)*HID + h;
    unsigned* st = STb + (size_t)i*65*HID + h;
    float acc1 = 0.f, acc2 = 0.f;
    st[0] = 0u;
    #pragma unroll 4
    for (int k = 0; k < 64; ++k){
        float fv = f0[(size_t)k*HID] + f1[(size_t)k*HID] + f2[(size_t)k*HID];
        float g  = grids[k];            // row 0 (identical across depth)
        acc1 += fv;
        acc2  = fmaf(g, fv, acc2);
        __half2 hh = __halves2half2(__float2half_rn(acc1), __float2half_rn(-acc2));
        st[(size_t)(k+1)*HID] = *reinterpret_cast<unsigned*>(&hh);
    }
}

// h[b,:] = sum_i ( z*S1[i,K0,:] - S2[i,K0,:] )  [fp16 packed table, v_dot2_f32_f16]
__global__ __launch_bounds__(128) void k_gather(const float* __restrict__ x, const float* __restrict__ mmp,
                                                const unsigned* __restrict__ STb, float* __restrict__ h){
    __shared__ float s_zmin[256], s_inv[256];
    __shared__ uint2 pre[2][256];       // (half2(z,1) bits, byte-offset) per (row_local, i)
    const int tid = threadIdx.x;
    const int b0  = blockIdx.x * 2;

    for (int f = tid; f < 256; f += 128){
        float mn = 1e30f, mx = -1e30f;
        #pragma unroll
        for (int p = 0; p < 16; ++p){
            mn = fminf(mn, mmp[(size_t)p*512 + f]);
            mx = fmaxf(mx, mmp[(size_t)p*512 + 256 + f]);
        }
        s_zmin[f] = mn;
        s_inv[f]  = 1.0f / (mx - mn + 1e-6f);
    }
    __syncthreads();

    for (int idx = tid; idx < 2*256; idx += 128){
        int bl = idx >> 8, i = idx & 255;
        float z = (x[(size_t)(b0 + bl)*IN_DIM + i] - s_zmin[i]) * s_inv[i];
        int K0 = (int)(z * 63.0f) + 1;
        K0 = max(1, min(63, K0));
        unsigned off = ((unsigned)(i*65 + K0)) << 9;    // row stride = 128 u32 = 512 B
        __half2 zh = __halves2half2(__float2half_rn(z), __float2half_rn(1.0f));
        pre[bl][i] = make_uint2(*reinterpret_cast<unsigned*>(&zh), off);
    }
    __syncthreads();

    const int w  = tid >> 6;            // wave id = local row
    const int l  = tid & 63;
    const int hl = l & 31;              // h-group lane: covers h = 4*hl .. 4*hl+3
    const int hi = l >> 5;              // 0: i in [0,128), 1: i in [128,256)
    const char* base = (const char*)STb + (size_t)hl * 16;
    const uint2* pp = &pre[w][hi * 128];
    float acc0 = 0.f, acc1 = 0.f, acc2 = 0.f, acc3 = 0.f;
    #pragma unroll 8
    for (int ii = 0; ii < 128; ++ii){
        uint2 p = pp[ii];               // uniform per half-wave -> broadcast
        uint4 u = *reinterpret_cast<const uint4*>(base + p.y);
        h2 zz = as_h2(p.x);
        acc0 = __builtin_amdgcn_fdot2(zz, as_h2(u.x), acc0, false);
        acc1 = __builtin_amdgcn_fdot2(zz, as_h2(u.y), acc1, false);
        acc2 = __builtin_amdgcn_fdot2(zz, as_h2(u.z), acc2, false);
        acc3 = __builtin_amdgcn_fdot2(zz, as_h2(u.w), acc3, false);
    }
    acc0 += __shfl(acc0, hl + 32);
    acc1 += __shfl(acc1, hl + 32);
    acc2 += __shfl(acc2, hl + 32);
    acc3 += __shfl(acc3, hl + 32);
    if (hi == 0){
        *reinterpret_cast<float4*>(&h[(size_t)(b0 + w)*HID + 4*hl]) =
            make_float4(acc0, acc1, acc2, acc3);
    }
}

// partial-reduce stats: pint[pc][j] = sum over 16 rows of part chunk pc.
// grid (twoN/256, PCHUNKS) -> 16 loads/thread, many waves (latency-tolerant)
__global__ __launch_bounds__(256) void k_stats(const float* __restrict__ part, float* __restrict__ pint,
                                               int twoN){
    int j = blockIdx.x*256 + threadIdx.x;
    if (j >= twoN) return;
    const int p0 = blockIdx.y * (GEMM_GB/PCHUNKS);
    float s = 0.f;
    #pragma unroll
    for (int p = 0; p < GEMM_GB/PCHUNKS; ++p) s += part[(size_t)(p0 + p)*twoN + j];
    pint[(size_t)blockIdx.y*twoN + j] = s;
}

// fp32 GEMM: C = relu(bn(A) @ W + bias); per-column stats -> per-block partials.
// BN input stats summed from pint[PCHUNKS][2K] in preamble (16 loads per k — cheap).
// tile 16x64, KC=64, 256 threads, micro-tile 1x4; grid (N/64, 256)
template<int BN_IN>
__global__ __launch_bounds__(256) void k_gemm(const float* __restrict__ A, const float* __restrict__ W,
                                              const float* __restrict__ bias,
                                              const float* __restrict__ pint,
                                              const float* __restrict__ gam, const float* __restrict__ bet,
                                              float* __restrict__ C, float* __restrict__ outpart,
                                              int K, int N){
    __shared__ float As[16][64];
    __shared__ float Ws[64][64];
    __shared__ float bnsc[256], bnsh[256];
    __shared__ float red[16][16][8];

    const int tid = threadIdx.x;
    const int n0  = blockIdx.x * 64;
    const int b0  = blockIdx.y * 16;

    if (BN_IN){
        for (int k = tid; k < K; k += 256){
            float s = 0.f, ss = 0.f;
            #pragma unroll
            for (int r = 0; r < PCHUNKS; ++r){
                s  += pint[(size_t)r*(2*K) + k];
                ss += pint[(size_t)r*(2*K) + K + k];
            }
            float m  = s  * (1.0f/BATCH);
            float v  = ss * (1.0f/BATCH) - m*m;
            float rs = rsqrtf(v + BN_EPS);
            float sc = gam[k]*rs;
            bnsc[k] = sc;
            bnsh[k] = fmaf(-m, sc, bet[k]);
        }
        __syncthreads();
    }

    const int nt = tid & 15;
    const int bt = tid >> 4;
    float acc[4] = {0.f, 0.f, 0.f, 0.f};

    for (int kc = 0; kc < K; kc += 64){
        #pragma unroll
        for (int idx = tid; idx < 16*64; idx += 256){
            int r = idx >> 6, k = idx & 63;
            float a = A[(size_t)(b0 + r)*K + kc + k];
            if (BN_IN) a = fmaf(a, bnsc[kc + k], bnsh[kc + k]);
            As[r][k] = a;
        }
        #pragma unroll
        for (int idx = tid; idx < 64*64; idx += 256){
            int k = idx >> 6, n = idx & 63;
            Ws[k][n] = W[(size_t)(kc + k)*N + n0 + n];
        }
        __syncthreads();
        #pragma unroll
        for (int k = 0; k < 64; ++k){
            float4 w = *reinterpret_cast<const float4*>(&Ws[k][nt*4]);
            float a0 = As[bt][k];
            acc[0] = fmaf(a0, w.x, acc[0]); acc[1] = fmaf(a0, w.y, acc[1]);
            acc[2] = fmaf(a0, w.z, acc[2]); acc[3] = fmaf(a0, w.w, acc[3]);
        }
        __syncthreads();
    }

    float vv[4];
    #pragma unroll
    for (int j = 0; j < 4; ++j){
        float v1 = acc[j] + bias[n0 + nt*4 + j];
        vv[j] = fmaxf(v1, 0.f);
    }
    *reinterpret_cast<float4*>(&C[(size_t)(b0 + bt)*N + n0 + nt*4]) =
        make_float4(vv[0], vv[1], vv[2], vv[3]);
    #pragma unroll
    for (int j = 0; j < 4; ++j){
        red[bt][nt][j]   = vv[j];
        red[bt][nt][4+j] = vv[j]*vv[j];
    }
    __syncthreads();
    for (int s = 8; s > 0; s >>= 1){
        if (bt < s){
            #pragma unroll
            for (int f = 0; f < 8; ++f) red[bt][nt][f] += red[bt+s][nt][f];
        }
        __syncthreads();
    }
    if (bt == 0){
        float* op = outpart + (size_t)blockIdx.y*(2*N);
        #pragma unroll
        for (int j = 0; j < 4; ++j){
            op[n0 + nt*4 + j]     = red[0][nt][j];
            op[N + n0 + nt*4 + j] = red[0][nt][4+j];
        }
    }
}

// out = BN(A3) @ w4 + b4   (reduces p3[256][128] in preamble — 16 blocks, L2-hot)
__global__ __launch_bounds__(256) void k_final(const float* __restrict__ A3, const float* __restrict__ p3,
                                               const float* __restrict__ g3, const float* __restrict__ be3,
                                               const float* __restrict__ w4, const float* __restrict__ b4,
                                               float* __restrict__ out){
    __shared__ float psum[2][128];
    __shared__ float sc[64], sh[64];
    const int t = threadIdx.x;
    {
        int j = t & 127, half = t >> 7;
        float s = 0.f;
        #pragma unroll 8
        for (int p = half*128; p < half*128 + 128; ++p) s += p3[(size_t)p*128 + j];
        psum[half][j] = s;
    }
    __syncthreads();
    if (t < 64){
        float s  = psum[0][t]      + psum[1][t];
        float ss = psum[0][64 + t] + psum[1][64 + t];
        float m  = s  * (1.0f/BATCH);
        float v  = ss * (1.0f/BATCH) - m*m;
        float rs = rsqrtf(v + BN_EPS);
        float g  = g3[t]*rs;
        sc[t] = g * w4[t];
        sh[t] = fmaf(-m, g, be3[t]) * w4[t];
    }
    __syncthreads();
    int row = blockIdx.x*256 + t;
    const float* a = A3 + (size_t)row*64;
    float acc = b4[0];
    #pragma unroll
    for (int k = 0; k < 64; ++k){
        acc = fmaf(a[k], sc[k], acc);
        acc += sh[k];
    }
    out[row] = acc;
}

extern "C" void kernel_launch(void* const* d_in, const int* in_sizes, int n_in,
                              void* d_out, int out_size, void* d_ws, size_t ws_size,
                              hipStream_t stream){
    const float* x     = (const float*)d_in[0];
    const float* fs    = (const float*)d_in[1];
    const float* grids = (const float*)d_in[2];
    const float* w1 = (const float*)d_in[3];  const float* b1 = (const float*)d_in[4];
    const float* g1 = (const float*)d_in[5];  const float* be1= (const float*)d_in[6];
    const float* w2 = (const float*)d_in[7];  const float* b2 = (const float*)d_in[8];
    const float* g2 = (const float*)d_in[9];  const float* be2= (const float*)d_in[10];
    const float* w3 = (const float*)d_in[11]; const float* b3 = (const float*)d_in[12];
    const float* g3 = (const float*)d_in[13]; const float* be3= (const float*)d_in[14];
    const float* w4 = (const float*)d_in[15]; const float* b4 = (const float*)d_in[16];
    float* out = (float*)d_out;

    char* ws = (char*)d_ws;
    float* mmp    = (float*)(ws + O_MMP);
    float* p1     = (float*)(ws + O_P1);
    float* p2     = (float*)(ws + O_P2);
    float* p3     = (float*)(ws + O_P3);
    float* pi1    = (float*)(ws + O_PI1);
    float* pi2    = (float*)(ws + O_PI2);
    unsigned* STb = (unsigned*)(ws + O_STB);
    float* A1     = (float*)(ws + O_A1);
    float* A2     = (float*)(ws + O_A2);
    float* A3     = (float*)(ws + O_A3);
    float* h      = A1;   // reuse A1's space? NO — h is separate; use tail region
    h = (float*)(ws + O_A3 + (size_t)4096*64*4);     // h: 4096*128 f after A3

    k_prep<<<144, 256, 0, stream>>>(x, fs, grids, mmp, STb);
    k_gather<<<2048, 128, 0, stream>>>(x, mmp, STb, h);
    k_gemm<0><<<dim3(4, 256), 256, 0, stream>>>(h,  w1, b1, nullptr, nullptr, nullptr, A1, p1, 128, 256);
    k_stats<<<dim3(2, PCHUNKS), 256, 0, stream>>>(p1, pi1, 512);
    k_gemm<1><<<dim3(2, 256), 256, 0, stream>>>(A1, w2, b2, pi1, g1, be1, A2, p2, 256, 128);
    k_stats<<<dim3(1, PCHUNKS), 256, 0, stream>>>(p2, pi2, 256);
    k_gemm<1><<<dim3(1, 256), 256, 0, stream>>>(A2, w3, b3, pi2, g2, be2, A3, p3, 128, 64);
    k_final<<<16, 256, 0, stream>>>(A3, p3, g3, be3, w4, b4, out);
}